// Round 2
// baseline (305.214 us; speedup 1.0000x reference)
//
#include <hip/hip_runtime.h>
#include <hip/hip_bf16.h>

#define BATCH 2
#define SEQ   2048
#define EMBED 1024
#define HEADS 16
#define HDIM  64
#define NBH   (BATCH*HEADS)

typedef __attribute__((ext_vector_type(8))) short short8;
typedef __attribute__((ext_vector_type(4))) float floatx4;
typedef unsigned short u16;
typedef unsigned int   u32;

// async global->LDS, 16B per lane. LDS dest must be wave-uniform base + lane*16.
__device__ __forceinline__ void async_cp16(const void* g, void* l) {
  __builtin_amdgcn_global_load_lds((const __attribute__((address_space(1))) void*)g,
                                   (__attribute__((address_space(3))) void*)l,
                                   16, 0, 0);
}

__device__ __forceinline__ u16 f2b(float f) {  // f32 -> bf16 RNE
  union { float f; u32 u; } x; x.f = f;
  return (u16)((x.u + 0x7fffu + ((x.u >> 16) & 1u)) >> 16);
}

// ---------------------------------------------------------------------------
// f32 -> bf16 conversion of x (1,048,576 f4), qkv_w (786,432 f4), out_w
// (262,144 f4). Block = 256 float4s; all region boundaries block-aligned.
// ---------------------------------------------------------------------------
__global__ __launch_bounds__(256)
void cvt_all(const float* __restrict__ x, const float* __restrict__ wqkv,
             const float* __restrict__ wo,
             u16* __restrict__ xb, u16* __restrict__ wqkvb, u16* __restrict__ wob) {
  const size_t t = (size_t)blockIdx.x * 256 + threadIdx.x;   // float4 index
  const float* src; u16* dst; size_t off;
  if (t < 1048576) { src = x; dst = xb; off = t; }
  else if (t < 1048576 + 786432) { src = wqkv; dst = wqkvb; off = t - 1048576; }
  else { src = wo; dst = wob; off = t - (1048576 + 786432); }
  float4 v = *(const float4*)(src + off * 4);
  ushort4 o;
  o.x = f2b(v.x); o.y = f2b(v.y); o.z = f2b(v.z); o.w = f2b(v.w);
  *(ushort4*)(dst + off * 4) = o;
}

// ---------------------------------------------------------------------------
// QKV GEMM: C[m,n] = sum_k X[m,k] * W[n,k];  M=4096, N=3072, K=1024 (NT, bf16)
// 128x128 tile, 4 waves of 64x64, 16x16x32 bf16 MFMA, global_load_lds staging.
// Epilogue scatters into q/k/v workspaces laid out [b*H+h][s][d].
// ---------------------------------------------------------------------------
__global__ __launch_bounds__(256, 2)
void qkv_gemm(const u16* __restrict__ X, const u16* __restrict__ W,
              u16* __restrict__ q_ws, u16* __restrict__ k_ws, u16* __restrict__ v_ws) {
  __shared__ u16 As[4][128][8];   // [k/8][row][8] : chunk c = kb*128+row, lane-contiguous
  __shared__ u16 Bs[4][128][8];
  const int tid  = threadIdx.x;
  const int lane = tid & 63, wv = tid >> 6;
  const int l15  = lane & 15, quad = lane >> 4;
  const int wm = (wv >> 1) << 6, wn = (wv & 1) << 6;
  const int m0 = blockIdx.y << 7, n0 = blockIdx.x << 7;

  floatx4 acc[4][4];
#pragma unroll
  for (int i = 0; i < 4; ++i)
#pragma unroll
    for (int j = 0; j < 4; ++j) acc[i][j] = {0.f, 0.f, 0.f, 0.f};

  for (int k0 = 0; k0 < EMBED; k0 += 32) {
    __syncthreads();
#pragma unroll
    for (int i = 0; i < 2; ++i) {
      int c = tid + (i << 8);
      int kb = c >> 7, row = c & 127;
      async_cp16(X + (size_t)(m0 + row) * EMBED + k0 + kb * 8, &As[kb][row][0]);
      async_cp16(W + (size_t)(n0 + row) * EMBED + k0 + kb * 8, &Bs[kb][row][0]);
    }
    __syncthreads();   // drains vmcnt(0): global_load_lds complete

    short8 af[4], bf[4];
#pragma unroll
    for (int t = 0; t < 4; ++t) {
      af[t] = *(const short8*)&As[quad][wm + t * 16 + l15][0];
      bf[t] = *(const short8*)&Bs[quad][wn + t * 16 + l15][0];
    }
#pragma unroll
    for (int i = 0; i < 4; ++i)
#pragma unroll
      for (int j = 0; j < 4; ++j)
        acc[i][j] = __builtin_amdgcn_mfma_f32_16x16x32_bf16(af[i], bf[j], acc[i][j], 0, 0, 0);
  }

  // C/D layout: col = lane&15, row = quad*4 + reg  (m89/m91-verified)
#pragma unroll
  for (int i = 0; i < 4; ++i) {
#pragma unroll
    for (int j = 0; j < 4; ++j) {
      int col = n0 + wn + j * 16 + l15;
      int c = col >> 10, hd = col & 1023;
      int h = hd >> 6, d = hd & 63;
      u16* dst = (c == 0) ? q_ws : (c == 1) ? k_ws : v_ws;
#pragma unroll
      for (int r = 0; r < 4; ++r) {
        int m = m0 + wm + i * 16 + quad * 4 + r;
        int b = m >> 11, s = m & 2047;
        dst[(((size_t)(b * HEADS + h)) * SEQ + s) * HDIM + d] = f2b(acc[i][j][r]);
      }
    }
  }
}

// ---------------------------------------------------------------------------
// Flash attention: one block = (bh, 64 q-rows); 4 waves, 16 q-rows each.
// Q frags in registers (pre-scaled by 1/8, exact), K via global_load_lds,
// V transposed into padded LDS, P through padded LDS for A-operand layout.
// ---------------------------------------------------------------------------
__global__ __launch_bounds__(256, 2)
void attn_kernel(const u16* __restrict__ q_ws, const u16* __restrict__ k_ws,
                 const u16* __restrict__ v_ws, const int* __restrict__ mask,
                 u16* __restrict__ ao) {
  __shared__ u16 Ks[8][64][8];    // [d/8][t][8], chunk c = kb*64+t (global_load_lds)
  __shared__ u16 Vt[64][88];      // V^T [d][t], stride 88 keeps b128 16B-aligned, ~2-way banks
  __shared__ u16 Ps[4][16][88];   // per-wave P [row][t]
  __shared__ float msk[64];

  const int tid  = threadIdx.x;
  const int lane = tid & 63, wv = tid >> 6;
  const int l15  = lane & 15, quad = lane >> 4;
  const int bh = blockIdx.y;
  const int b  = bh >> 4, h = bh & 15;
  const int qr = (blockIdx.x << 6) + (wv << 4);   // wave's first q row

  const u16* Qb = q_ws + (size_t)bh * SEQ * HDIM;
  const u16* Kb = k_ws + (size_t)bh * SEQ * HDIM;
  const u16* Vb = v_ws + (size_t)bh * SEQ * HDIM;

  // A-frag: A[m=lane&15][k=quad*8+j]; pre-scale by 0.125 (exponent-only, exact in bf16)
  short8 qf[2];
#pragma unroll
  for (int s = 0; s < 2; ++s) {
    short8 v = *(const short8*)(Qb + (size_t)(qr + l15) * HDIM + s * 32 + quad * 8);
#pragma unroll
    for (int e = 0; e < 8; ++e) {
      union { float f; u32 u; } x;
      x.u = ((u32)(u16)v[e]) << 16;
      x.f *= 0.125f;
      v[e] = (short)(x.u >> 16);
    }
    qf[s] = v;
  }

  float m_run[4], l_run[4];
  floatx4 O[4];
#pragma unroll
  for (int r = 0; r < 4; ++r) { m_run[r] = -1e30f; l_run[r] = 0.f; }
#pragma unroll
  for (int dt = 0; dt < 4; ++dt) O[dt] = {0.f, 0.f, 0.f, 0.f};

  for (int t0 = 0; t0 < SEQ; t0 += 64) {
    __syncthreads();
    // K tile: 512 chunks of 16B
#pragma unroll
    for (int i = 0; i < 2; ++i) {
      int c = tid + (i << 8);
      int kb = c >> 6, t = c & 63;
      async_cp16(Kb + (size_t)(t0 + t) * HDIM + kb * 8, &Ks[kb][t][0]);
    }
    // V tile transposed: thread handles rows 2p,2p+1, cols d0..d0+7; packed u32 writes
    {
      int p = tid >> 3, d0 = (tid & 7) * 8;
      const u16* vp = Vb + (size_t)(t0 + 2 * p) * HDIM + d0;
      short8 r0 = *(const short8*)vp;
      short8 r1 = *(const short8*)(vp + HDIM);
#pragma unroll
      for (int j = 0; j < 8; ++j) {
        u32 pk = ((u32)(u16)r0[j]) | (((u32)(u16)r1[j]) << 16);
        *(u32*)&Vt[d0 + j][2 * p] = pk;
      }
    }
    if (tid < 64) msk[tid] = mask[b * SEQ + t0 + tid] ? 0.f : -1e30f;
    __syncthreads();

    // S = (Q/8) K^T : 4 col-tiles x 2 k-steps
    floatx4 sc[4];
#pragma unroll
    for (int nt = 0; nt < 4; ++nt) {
      sc[nt] = {0.f, 0.f, 0.f, 0.f};
#pragma unroll
      for (int s = 0; s < 2; ++s) {
        short8 kf = *(const short8*)&Ks[s * 4 + quad][nt * 16 + l15][0];
        sc[nt] = __builtin_amdgcn_mfma_f32_16x16x32_bf16(qf[s], kf, sc[nt], 0, 0, 0);
      }
      float mc = msk[nt * 16 + l15];
#pragma unroll
      for (int r = 0; r < 4; ++r) sc[nt][r] += mc;
    }

    // online softmax; lane owns rows quad*4+r, cols lane&15 (+nt*16)
    float mt[4], al[4], rs[4];
#pragma unroll
    for (int r = 0; r < 4; ++r) {
      mt[r] = fmaxf(fmaxf(sc[0][r], sc[1][r]), fmaxf(sc[2][r], sc[3][r]));
#pragma unroll
      for (int off = 1; off < 16; off <<= 1)
        mt[r] = fmaxf(mt[r], __shfl_xor(mt[r], off, 16));
      float mn = fmaxf(m_run[r], mt[r]);
      al[r] = __expf(m_run[r] - mn);
      m_run[r] = mn;
      rs[r] = 0.f;
    }
#pragma unroll
    for (int nt = 0; nt < 4; ++nt) {
#pragma unroll
      for (int r = 0; r < 4; ++r) {
        float p = __expf(sc[nt][r] - m_run[r]);
        rs[r] += p;
        Ps[wv][quad * 4 + r][nt * 16 + l15] = f2b(p);
      }
    }
#pragma unroll
    for (int r = 0; r < 4; ++r) {
#pragma unroll
      for (int off = 1; off < 16; off <<= 1) rs[r] += __shfl_xor(rs[r], off, 16);
      l_run[r] = l_run[r] * al[r] + rs[r];
    }
#pragma unroll
    for (int dt = 0; dt < 4; ++dt)
#pragma unroll
      for (int r = 0; r < 4; ++r) O[dt][r] *= al[r];

    // O += P V : A = Ps (wave-local LDS round-trip), B = Vt
    short8 pf[2];
#pragma unroll
    for (int s = 0; s < 2; ++s)
      pf[s] = *(const short8*)&Ps[wv][l15][s * 32 + quad * 8];
#pragma unroll
    for (int dt = 0; dt < 4; ++dt) {
#pragma unroll
      for (int s = 0; s < 2; ++s) {
        short8 vf = *(const short8*)&Vt[dt * 16 + l15][s * 32 + quad * 8];
        O[dt] = __builtin_amdgcn_mfma_f32_16x16x32_bf16(pf[s], vf, O[dt], 0, 0, 0);
      }
    }
  }

  // normalize + write attn output as (b, s, h*64+d)
#pragma unroll
  for (int r = 0; r < 4; ++r) {
    float inv = 1.f / l_run[r];
    int srow = qr + quad * 4 + r;
#pragma unroll
    for (int dt = 0; dt < 4; ++dt) {
      int d = dt * 16 + l15;
      ao[((size_t)(b * SEQ + srow)) * EMBED + h * 64 + d] = f2b(O[dt][r] * inv);
    }
  }
}

// ---------------------------------------------------------------------------
// Output projection: out[m,n] = sum_k AO[m,k]*Wo[n,k] + bias[n]; M=4096,N=1024
// bias is f32 input, output is f32.
// ---------------------------------------------------------------------------
__global__ __launch_bounds__(256, 2)
void proj_gemm(const u16* __restrict__ A, const u16* __restrict__ W,
               const float* __restrict__ bias, float* __restrict__ out) {
  __shared__ u16 As[4][128][8];
  __shared__ u16 Bs[4][128][8];
  const int tid  = threadIdx.x;
  const int lane = tid & 63, wv = tid >> 6;
  const int l15  = lane & 15, quad = lane >> 4;
  const int wm = (wv >> 1) << 6, wn = (wv & 1) << 6;
  const int m0 = blockIdx.y << 7, n0 = blockIdx.x << 7;

  floatx4 acc[4][4];
#pragma unroll
  for (int i = 0; i < 4; ++i)
#pragma unroll
    for (int j = 0; j < 4; ++j) acc[i][j] = {0.f, 0.f, 0.f, 0.f};

  for (int k0 = 0; k0 < EMBED; k0 += 32) {
    __syncthreads();
#pragma unroll
    for (int i = 0; i < 2; ++i) {
      int c = tid + (i << 8);
      int kb = c >> 7, row = c & 127;
      async_cp16(A + (size_t)(m0 + row) * EMBED + k0 + kb * 8, &As[kb][row][0]);
      async_cp16(W + (size_t)(n0 + row) * EMBED + k0 + kb * 8, &Bs[kb][row][0]);
    }
    __syncthreads();

    short8 af[4], bf[4];
#pragma unroll
    for (int t = 0; t < 4; ++t) {
      af[t] = *(const short8*)&As[quad][wm + t * 16 + l15][0];
      bf[t] = *(const short8*)&Bs[quad][wn + t * 16 + l15][0];
    }
#pragma unroll
    for (int i = 0; i < 4; ++i)
#pragma unroll
      for (int j = 0; j < 4; ++j)
        acc[i][j] = __builtin_amdgcn_mfma_f32_16x16x32_bf16(af[i], bf[j], acc[i][j], 0, 0, 0);
  }

#pragma unroll
  for (int i = 0; i < 4; ++i) {
#pragma unroll
    for (int j = 0; j < 4; ++j) {
      int col = n0 + wn + j * 16 + l15;
      float bv = bias[col];
#pragma unroll
      for (int r = 0; r < 4; ++r) {
        int m = m0 + wm + i * 16 + quad * 4 + r;
        out[(size_t)m * EMBED + col] = acc[i][j][r] + bv;
      }
    }
  }
}

extern "C" void kernel_launch(void* const* d_in, const int* in_sizes, int n_in,
                              void* d_out, int out_size, void* d_ws, size_t ws_size,
                              hipStream_t stream) {
  const float* x     = (const float*)d_in[0];
  const int*   mask  = (const int*)d_in[1];
  const float* qkv_w = (const float*)d_in[2];
  const float* out_w = (const float*)d_in[3];
  const float* out_b = (const float*)d_in[4];
  float* out = (float*)d_out;

  const size_t per = (size_t)NBH * SEQ * HDIM;      // 4,194,304 elems
  u16* xb    = (u16*)d_ws;                          // 4,194,304
  u16* wqkvb = xb + 4194304;                        // 3,145,728
  u16* wob   = wqkvb + 3145728;                     // 1,048,576
  u16* q_ws  = wob + 1048576;
  u16* k_ws  = q_ws + per;
  u16* v_ws  = k_ws + per;
  u16* ao    = v_ws + per;                          // 4096 x 1024

  cvt_all<<<8192, 256, 0, stream>>>(x, qkv_w, out_w, xb, wqkvb, wob);
  qkv_gemm<<<dim3(24, 32), 256, 0, stream>>>(xb, wqkvb, q_ws, k_ws, v_ws);
  attn_kernel<<<dim3(SEQ / 64, NBH), 256, 0, stream>>>(q_ws, k_ws, v_ws, mask, ao);
  proj_gemm<<<dim3(8, 32), 256, 0, stream>>>(ao, wob, out_b, out);
}

// Round 3
// 254.080 us; speedup vs baseline: 1.2013x; 1.2013x over previous
//
#include <hip/hip_runtime.h>
#include <hip/hip_bf16.h>

#define BATCH 2
#define SEQ   2048
#define EMBED 1024
#define HEADS 16
#define HDIM  64
#define NBH   (BATCH*HEADS)

typedef __attribute__((ext_vector_type(8))) short short8;
typedef __attribute__((ext_vector_type(4))) float floatx4;
typedef unsigned short u16;
typedef unsigned int   u32;

// async global->LDS, 16B per lane. LDS dest must be wave-uniform base + lane*16.
__device__ __forceinline__ void async_cp16(const void* g, void* l) {
  __builtin_amdgcn_global_load_lds((const __attribute__((address_space(1))) void*)g,
                                   (__attribute__((address_space(3))) void*)l,
                                   16, 0, 0);
}

__device__ __forceinline__ u16 f2b(float f) {  // f32 -> bf16 RNE
  union { float f; u32 u; } x; x.f = f;
  return (u16)((x.u + 0x7fffu + ((x.u >> 16) & 1u)) >> 16);
}
__device__ __forceinline__ u32 pk2(float a, float b) {  // packed bf16x2
  __hip_bfloat162 t = __float22bfloat162_rn(make_float2(a, b));
  return *reinterpret_cast<u32*>(&t);
}

// ---------------------------------------------------------------------------
// f32 -> bf16 conversion of x, qkv_w, out_w (region bounds block-aligned).
// ---------------------------------------------------------------------------
__global__ __launch_bounds__(256)
void cvt_all(const float* __restrict__ x, const float* __restrict__ wqkv,
             const float* __restrict__ wo,
             u16* __restrict__ xb, u16* __restrict__ wqkvb, u16* __restrict__ wob) {
  const size_t t = (size_t)blockIdx.x * 256 + threadIdx.x;   // float4 index
  const float* src; u16* dst; size_t off;
  if (t < 1048576) { src = x; dst = xb; off = t; }
  else if (t < 1048576 + 786432) { src = wqkv; dst = wqkvb; off = t - 1048576; }
  else { src = wo; dst = wob; off = t - (1048576 + 786432); }
  float4 v = *(const float4*)(src + off * 4);
  ushort4 o;
  o.x = f2b(v.x); o.y = f2b(v.y); o.z = f2b(v.z); o.w = f2b(v.w);
  *(ushort4*)(dst + off * 4) = o;
}

// ---------------------------------------------------------------------------
// QKV GEMM: C[m,n] = sum_k X[m,k] * W[n,k];  M=4096, N=3072, K=1024 (NT, bf16)
// ---------------------------------------------------------------------------
__global__ __launch_bounds__(256, 2)
void qkv_gemm(const u16* __restrict__ X, const u16* __restrict__ W,
              u16* __restrict__ q_ws, u16* __restrict__ k_ws, u16* __restrict__ v_ws) {
  __shared__ u16 As[4][128][8];
  __shared__ u16 Bs[4][128][8];
  const int tid  = threadIdx.x;
  const int lane = tid & 63, wv = tid >> 6;
  const int l15  = lane & 15, quad = lane >> 4;
  const int wm = (wv >> 1) << 6, wn = (wv & 1) << 6;
  const int m0 = blockIdx.y << 7, n0 = blockIdx.x << 7;

  floatx4 acc[4][4];
#pragma unroll
  for (int i = 0; i < 4; ++i)
#pragma unroll
    for (int j = 0; j < 4; ++j) acc[i][j] = {0.f, 0.f, 0.f, 0.f};

  for (int k0 = 0; k0 < EMBED; k0 += 32) {
    __syncthreads();
#pragma unroll
    for (int i = 0; i < 2; ++i) {
      int c = tid + (i << 8);
      int kb = c >> 7, row = c & 127;
      async_cp16(X + (size_t)(m0 + row) * EMBED + k0 + kb * 8, &As[kb][row][0]);
      async_cp16(W + (size_t)(n0 + row) * EMBED + k0 + kb * 8, &Bs[kb][row][0]);
    }
    __syncthreads();

    short8 af[4], bf[4];
#pragma unroll
    for (int t = 0; t < 4; ++t) {
      af[t] = *(const short8*)&As[quad][wm + t * 16 + l15][0];
      bf[t] = *(const short8*)&Bs[quad][wn + t * 16 + l15][0];
    }
#pragma unroll
    for (int i = 0; i < 4; ++i)
#pragma unroll
      for (int j = 0; j < 4; ++j)
        acc[i][j] = __builtin_amdgcn_mfma_f32_16x16x32_bf16(af[i], bf[j], acc[i][j], 0, 0, 0);
  }

#pragma unroll
  for (int i = 0; i < 4; ++i) {
#pragma unroll
    for (int j = 0; j < 4; ++j) {
      int col = n0 + wn + j * 16 + l15;
      int c = col >> 10, hd = col & 1023;
      int h = hd >> 6, d = hd & 63;
      u16* dst = (c == 0) ? q_ws : (c == 1) ? k_ws : v_ws;
#pragma unroll
      for (int r = 0; r < 4; ++r) {
        int m = m0 + wm + i * 16 + quad * 4 + r;
        int b = m >> 11, s = m & 2047;
        dst[(((size_t)(b * HEADS + h)) * SEQ + s) * HDIM + d] = f2b(acc[i][j][r]);
      }
    }
  }
}

// ---------------------------------------------------------------------------
// Flash attention v2: S^T = K·Q^T so softmax rows live in-lane.
// Block = (bh, 128 q); 4 waves x 32 q. KV tile 64. Q frags in regs (x1/8).
// ---------------------------------------------------------------------------
__global__ __launch_bounds__(256, 2)
void attn_kernel(const u16* __restrict__ q_ws, const u16* __restrict__ k_ws,
                 const u16* __restrict__ v_ws, const int* __restrict__ mask,
                 u16* __restrict__ ao) {
  __shared__ u16 Ks[8][64][8];     // 8 KB  [d/8][t][8] via global_load_lds
  __shared__ u16 Vt[64][72];       // 9 KB  V^T [d][t+pad]; stride 144B (16B-aligned)
  __shared__ u16 Ps[128][72];      // 18 KB P [q][t+pad], each wave owns 32 rows
  __shared__ float msk[64];
  __shared__ float abuf[4][32];

  const int tid  = threadIdx.x;
  const int lane = tid & 63, wv = tid >> 6;
  const int l15  = lane & 15, quad = lane >> 4;
  const int bh = blockIdx.y;
  const int b  = bh >> 4, h = bh & 15;
  const int qrw = (blockIdx.x << 7) + (wv << 5);   // wave's first q row (32 q/wave)

  const u16* Qb = q_ws + (size_t)bh * SEQ * HDIM;
  const u16* Kb = k_ws + (size_t)bh * SEQ * HDIM;
  const u16* Vb = v_ws + (size_t)bh * SEQ * HDIM;

  // Q B-frags: B[k=d=quad*8+j][n=q=l15], pre-scaled by 1/8 (exact in bf16)
  short8 qf[2][2];
#pragma unroll
  for (int qh = 0; qh < 2; ++qh)
#pragma unroll
    for (int s = 0; s < 2; ++s) {
      short8 v = *(const short8*)(Qb + (size_t)(qrw + qh * 16 + l15) * HDIM + s * 32 + quad * 8);
#pragma unroll
      for (int e = 0; e < 8; ++e) {
        union { float f; u32 u; } x;
        x.u = ((u32)(u16)v[e]) << 16;
        x.f *= 0.125f;
        v[e] = (short)(x.u >> 16);
      }
      qf[qh][s] = v;
    }

  float m_run[2] = {-1e30f, -1e30f}, l_run[2] = {0.f, 0.f};
  floatx4 O[2][4];
#pragma unroll
  for (int qh = 0; qh < 2; ++qh)
#pragma unroll
    for (int dt = 0; dt < 4; ++dt) O[qh][dt] = {0.f, 0.f, 0.f, 0.f};

  // V prefetch regs for tile 0: thread covers rows 2p,2p+1, cols d0..d0+7
  const int p = tid >> 3, d0 = (tid & 7) * 8;
  short8 vr0 = *(const short8*)(Vb + (size_t)(2 * p) * HDIM + d0);
  short8 vr1 = *(const short8*)(Vb + (size_t)(2 * p + 1) * HDIM + d0);

  for (int t0 = 0; t0 < SEQ; t0 += 64) {
    __syncthreads();
    // stage K tile (async) : 512 chunks of 16B
#pragma unroll
    for (int i = 0; i < 2; ++i) {
      int c = tid + (i << 8);
      int kb = c >> 6, t = c & 63;
      async_cp16(Kb + (size_t)(t0 + t) * HDIM + kb * 8, &Ks[kb][t][0]);
    }
    // V^T from prefetched regs (packed u32 writes)
#pragma unroll
    for (int j = 0; j < 8; ++j) {
      u32 pk = ((u32)(u16)vr0[j]) | (((u32)(u16)vr1[j]) << 16);
      *(u32*)&Vt[d0 + j][2 * p] = pk;
    }
    if (tid < 64) msk[tid] = mask[b * SEQ + t0 + tid] ? 0.f : -1e30f;
    __syncthreads();

    // prefetch next V tile into regs (overlaps compute below)
    if (t0 + 64 < SEQ) {
      vr0 = *(const short8*)(Vb + (size_t)(t0 + 64 + 2 * p) * HDIM + d0);
      vr1 = *(const short8*)(Vb + (size_t)(t0 + 64 + 2 * p + 1) * HDIM + d0);
    }

    // S^T = K·(Q/8)^T : D[t=quad*4+r+nt*16][q=l15]
    floatx4 sc0[4], sc1[4];
#pragma unroll
    for (int nt = 0; nt < 4; ++nt) {
      sc0[nt] = {0.f, 0.f, 0.f, 0.f};
      sc1[nt] = {0.f, 0.f, 0.f, 0.f};
#pragma unroll
      for (int s = 0; s < 2; ++s) {
        short8 kf = *(const short8*)&Ks[s * 4 + quad][nt * 16 + l15][0];
        sc0[nt] = __builtin_amdgcn_mfma_f32_16x16x32_bf16(kf, qf[0][s], sc0[nt], 0, 0, 0);
        sc1[nt] = __builtin_amdgcn_mfma_f32_16x16x32_bf16(kf, qf[1][s], sc1[nt], 0, 0, 0);
      }
    }

    // mask + in-lane max over this lane's 16 t's, then cross-quad (2 shuffles)
    float mt0 = -1e30f, mt1 = -1e30f;
#pragma unroll
    for (int nt = 0; nt < 4; ++nt) {
      const float4 m4 = *(const float4*)&msk[nt * 16 + quad * 4];
#pragma unroll
      for (int r = 0; r < 4; ++r) {
        float mr = (&m4.x)[r];
        sc0[nt][r] += mr; sc1[nt][r] += mr;
        mt0 = fmaxf(mt0, sc0[nt][r]);
        mt1 = fmaxf(mt1, sc1[nt][r]);
      }
    }
    mt0 = fmaxf(mt0, __shfl_xor(mt0, 16)); mt0 = fmaxf(mt0, __shfl_xor(mt0, 32));
    mt1 = fmaxf(mt1, __shfl_xor(mt1, 16)); mt1 = fmaxf(mt1, __shfl_xor(mt1, 32));

    const float mn0 = fmaxf(m_run[0], mt0), mn1 = fmaxf(m_run[1], mt1);
    const float al0 = __expf(m_run[0] - mn0), al1 = __expf(m_run[1] - mn1);
    m_run[0] = mn0; m_run[1] = mn1;

    // p = exp(s - m), in-lane sums, packed bf16 store of P (b64 per nt per qh)
    float rs0 = 0.f, rs1 = 0.f;
    const int prow0 = (wv << 5) + l15, pcol = quad << 2;
#pragma unroll
    for (int nt = 0; nt < 4; ++nt) {
      float p0[4], p1[4];
#pragma unroll
      for (int r = 0; r < 4; ++r) {
        p0[r] = __expf(sc0[nt][r] - mn0); rs0 += p0[r];
        p1[r] = __expf(sc1[nt][r] - mn1); rs1 += p1[r];
      }
      uint2 w0, w1;
      w0.x = pk2(p0[0], p0[1]); w0.y = pk2(p0[2], p0[3]);
      w1.x = pk2(p1[0], p1[1]); w1.y = pk2(p1[2], p1[3]);
      *(uint2*)&Ps[prow0][nt * 16 + pcol]      = w0;
      *(uint2*)&Ps[prow0 + 16][nt * 16 + pcol] = w1;
    }
    rs0 += __shfl_xor(rs0, 16); rs0 += __shfl_xor(rs0, 32);
    rs1 += __shfl_xor(rs1, 16); rs1 += __shfl_xor(rs1, 32);
    l_run[0] = l_run[0] * al0 + rs0;
    l_run[1] = l_run[1] * al1 + rs1;

    // broadcast alpha to O-layout (rows quad*4+r) via LDS bounce
    if (quad < 2) abuf[wv][(quad << 4) + l15] = quad ? al1 : al0;
    const float4 a0 = *(const float4*)&abuf[wv][quad << 2];
    const float4 a1 = *(const float4*)&abuf[wv][16 + (quad << 2)];
#pragma unroll
    for (int dt = 0; dt < 4; ++dt)
#pragma unroll
      for (int r = 0; r < 4; ++r) {
        O[0][dt][r] *= (&a0.x)[r];
        O[1][dt][r] *= (&a1.x)[r];
      }

    // O += P·V  (A = Ps rows, B = Vt)
#pragma unroll
    for (int tch = 0; tch < 2; ++tch) {
      short8 pf0 = *(const short8*)&Ps[prow0][tch * 32 + quad * 8];
      short8 pf1 = *(const short8*)&Ps[prow0 + 16][tch * 32 + quad * 8];
#pragma unroll
      for (int dt = 0; dt < 4; ++dt) {
        short8 vf = *(const short8*)&Vt[dt * 16 + l15][tch * 32 + quad * 8];
        O[0][dt] = __builtin_amdgcn_mfma_f32_16x16x32_bf16(pf0, vf, O[0][dt], 0, 0, 0);
        O[1][dt] = __builtin_amdgcn_mfma_f32_16x16x32_bf16(pf1, vf, O[1][dt], 0, 0, 0);
      }
    }
  }

  // final 1/l via same LDS bounce, then write ao (b, s, h*64+d)
  __syncthreads();
  if (quad < 2) abuf[wv][(quad << 4) + l15] = quad ? l_run[1] : l_run[0];
  const float4 li0 = *(const float4*)&abuf[wv][quad << 2];
  const float4 li1 = *(const float4*)&abuf[wv][16 + (quad << 2)];
#pragma unroll
  for (int qh = 0; qh < 2; ++qh) {
#pragma unroll
    for (int r = 0; r < 4; ++r) {
      float inv = 1.f / (qh ? (&li1.x)[r] : (&li0.x)[r]);
      int srow = qrw + qh * 16 + quad * 4 + r;
#pragma unroll
      for (int dt = 0; dt < 4; ++dt) {
        int d = dt * 16 + l15;
        ao[((size_t)(b * SEQ + srow)) * EMBED + h * 64 + d] = f2b(O[qh][dt][r] * inv);
      }
    }
  }
}

// ---------------------------------------------------------------------------
// Output projection: 128x64 tiles (grid 512 = 2/CU), f32 bias + f32 out.
// ---------------------------------------------------------------------------
__global__ __launch_bounds__(256, 2)
void proj_gemm(const u16* __restrict__ A, const u16* __restrict__ W,
               const float* __restrict__ bias, float* __restrict__ out) {
  __shared__ u16 As[4][128][8];
  __shared__ u16 Bs[4][64][8];
  const int tid  = threadIdx.x;
  const int lane = tid & 63, wv = tid >> 6;
  const int l15  = lane & 15, quad = lane >> 4;
  const int wm = (wv >> 1) << 6, wn = (wv & 1) << 5;
  const int m0 = blockIdx.y << 7, n0 = blockIdx.x << 6;

  floatx4 acc[4][2];
#pragma unroll
  for (int i = 0; i < 4; ++i)
#pragma unroll
    for (int j = 0; j < 2; ++j) acc[i][j] = {0.f, 0.f, 0.f, 0.f};

  for (int k0 = 0; k0 < EMBED; k0 += 32) {
    __syncthreads();
#pragma unroll
    for (int i = 0; i < 2; ++i) {
      int c = tid + (i << 8);
      int kb = c >> 7, row = c & 127;
      async_cp16(A + (size_t)(m0 + row) * EMBED + k0 + kb * 8, &As[kb][row][0]);
    }
    {
      int kb = tid >> 6, row = tid & 63;
      async_cp16(W + (size_t)(n0 + row) * EMBED + k0 + kb * 8, &Bs[kb][row][0]);
    }
    __syncthreads();

    short8 af[4], bf[2];
#pragma unroll
    for (int t = 0; t < 4; ++t)
      af[t] = *(const short8*)&As[quad][wm + t * 16 + l15][0];
#pragma unroll
    for (int t = 0; t < 2; ++t)
      bf[t] = *(const short8*)&Bs[quad][wn + t * 16 + l15][0];
#pragma unroll
    for (int i = 0; i < 4; ++i)
#pragma unroll
      for (int j = 0; j < 2; ++j)
        acc[i][j] = __builtin_amdgcn_mfma_f32_16x16x32_bf16(af[i], bf[j], acc[i][j], 0, 0, 0);
  }

#pragma unroll
  for (int i = 0; i < 4; ++i) {
#pragma unroll
    for (int j = 0; j < 2; ++j) {
      int col = n0 + wn + j * 16 + l15;
      float bv = bias[col];
#pragma unroll
      for (int r = 0; r < 4; ++r) {
        int m = m0 + wm + i * 16 + quad * 4 + r;
        out[(size_t)m * EMBED + col] = acc[i][j][r] + bv;
      }
    }
  }
}

extern "C" void kernel_launch(void* const* d_in, const int* in_sizes, int n_in,
                              void* d_out, int out_size, void* d_ws, size_t ws_size,
                              hipStream_t stream) {
  const float* x     = (const float*)d_in[0];
  const int*   mask  = (const int*)d_in[1];
  const float* qkv_w = (const float*)d_in[2];
  const float* out_w = (const float*)d_in[3];
  const float* out_b = (const float*)d_in[4];
  float* out = (float*)d_out;

  const size_t per = (size_t)NBH * SEQ * HDIM;      // 4,194,304 elems
  u16* xb    = (u16*)d_ws;                          // 4,194,304
  u16* wqkvb = xb + 4194304;                        // 3,145,728
  u16* wob   = wqkvb + 3145728;                     // 1,048,576
  u16* q_ws  = wob + 1048576;
  u16* k_ws  = q_ws + per;
  u16* v_ws  = k_ws + per;
  u16* ao    = v_ws + per;                          // 4096 x 1024

  cvt_all<<<8192, 256, 0, stream>>>(x, qkv_w, out_w, xb, wqkvb, wob);
  qkv_gemm<<<dim3(24, 32), 256, 0, stream>>>(xb, wqkvb, q_ws, k_ws, v_ws);
  attn_kernel<<<dim3(SEQ / 128, NBH), 256, 0, stream>>>(q_ws, k_ws, v_ws, mask, ao);
  proj_gemm<<<dim3(16, 32), 256, 0, stream>>>(ao, wob, out_b, out);
}